// Round 9
// baseline (75.738 us; speedup 1.0000x reference)
//
#include <hip/hip_runtime.h>

#define FD 128  // feature dim

typedef __attribute__((ext_vector_type(8))) short short8;   // 8 bf16
typedef __attribute__((ext_vector_type(4))) float f32x4;    // MFMA acc

__device__ __forceinline__ unsigned short f2bf(float f) {
    unsigned u = __float_as_uint(f);
    u += 0x7fff + ((u >> 16) & 1);   // round-to-nearest-even
    return (unsigned short)(u >> 16);
}
// exact signed-int8 dot of 4 packed bytes (int32 math, no precision loss)
__device__ __forceinline__ int bdot4(unsigned x, unsigned y) {
    int s;
    s  = (((int)(x << 24)) >> 24) * (((int)(y << 24)) >> 24);
    s += (((int)(x << 16)) >> 24) * (((int)(y << 16)) >> 24);
    s += (((int)(x <<  8)) >> 24) * (((int)(y <<  8)) >> 24);
    s += (((int)x) >> 24)         * (((int)y) >> 24);
    return s;
}
__device__ __forceinline__ unsigned pack4(float a, float b, float c, float d, float inv) {
    const int q0 = (int)rintf(a * inv), q1 = (int)rintf(b * inv);
    const int q2 = (int)rintf(c * inv), q3 = (int)rintf(d * inv);
    return (unsigned)(q0 & 255) | ((unsigned)(q1 & 255) << 8) |
           ((unsigned)(q2 & 255) << 16) | ((unsigned)(q3 & 255) << 24);
}

// ---------------------------------------------------------------------------
// Kernel 0: Wt[n][k] = bf16(W[k][n])  (128x128), short8 outputs.
// ---------------------------------------------------------------------------
__global__ void wt_kernel(const float* __restrict__ W, unsigned short* __restrict__ Wt) {
    const int tid = blockIdx.x * 256 + (int)threadIdx.x;   // 0..2047
    const int n  = tid & 127;
    const int k0 = (tid >> 7) * 8;
    short8 w;
    #pragma unroll
    for (int j = 0; j < 8; ++j) w[j] = (short)f2bf(W[(k0 + j) * FD + n]);
    *(short8*)(Wt + (size_t)n * FD + k0) = w;
}

// ---------------------------------------------------------------------------
// Kernel Z: per-row int8 quantization of z (direct from fp32).
// 32 lanes per row, 4 floats/lane (512B row read, 128B int8 row write).
// ---------------------------------------------------------------------------
__global__ __launch_bounds__(256)
void zquant(const float* __restrict__ z, unsigned char* __restrict__ z8,
            float* __restrict__ zscale, int nrows) {
    const int tid  = (int)threadIdx.x;
    const int lane = tid & 63;
    const int l32  = lane & 31;
    const long row = (long)(blockIdx.x * 4 + (tid >> 6)) * 2 + (lane >> 5);
    const long rc  = (row < nrows) ? row : (long)(nrows - 1);

    const float4 v = *(const float4*)(z + rc * FD + l32 * 4);
    float m = fmaxf(fmaxf(fabsf(v.x), fabsf(v.y)), fmaxf(fabsf(v.z), fabsf(v.w)));
    #pragma unroll
    for (int off = 1; off < 32; off <<= 1)
        m = fmaxf(m, __shfl_xor(m, off, 64));
    m = fmaxf(m, 1e-30f);
    const float inv = 127.0f / m;

    if (row < nrows) {
        *(unsigned*)(z8 + row * FD + l32 * 4) = pack4(v.x, v.y, v.z, v.w, inv);
        if (l32 == 0) zscale[row] = m * (1.0f / 127.0f);
    }
}

// ---------------------------------------------------------------------------
// Kernel 1 (v4): u8 = int8rowquant(z @ W) via MFMA 16x16x32 bf16.
// Wt staged in LDS (32 KB, XOR-swizzled). Epilogue repacks the fp32
// accumulator through LDS (4 waves x 8 KB = 32 KB, reusing Wt region after
// barrier), then row-max -> int8 quantize -> coalesced 4B stores + scale.
// No bf16 u and no zb are materialized (edge phase reads int8 only).
// ---------------------------------------------------------------------------
__global__ __launch_bounds__(256)
void u_mfma4(const float* __restrict__ z, const unsigned short* __restrict__ Wt,
             unsigned char* __restrict__ u8, float* __restrict__ uscale,
             int nrows) {
    __shared__ unsigned short Wl[FD * FD];  // 32 KB
    char* ldsb = (char*)Wl;
    const int tid  = (int)threadIdx.x;
    const int lane = tid & 63;
    const int wave = tid >> 6;
    const int l16  = lane & 15;
    const int kq   = lane >> 4;

    // stage Wt -> LDS, swizzled: byte = n*256 + (o ^ ((n&7)<<4))
    #pragma unroll
    for (int i = 0; i < 8; ++i) {
        const int c = i * 256 + tid;
        const int n = c >> 4;
        const int o = (c & 15) * 16;
        short8 v = *(const short8*)(Wt + (size_t)n * FD + (c & 15) * 8);
        *(short8*)(ldsb + n * 256 + (o ^ ((n & 7) << 4))) = v;
    }
    __syncthreads();

    const long rowbase = (long)blockIdx.x * 64 + wave * 16;
    const long r  = rowbase + l16;
    const long rc = (r < nrows) ? r : (long)(nrows - 1);

    f32x4 acc[8];
    #pragma unroll
    for (int nt = 0; nt < 8; ++nt)
        acc[nt] = (f32x4){0.f, 0.f, 0.f, 0.f};

    #pragma unroll
    for (int ks = 0; ks < 4; ++ks) {
        const int k0 = ks * 32 + kq * 8;
        const float4* zp = (const float4*)(z + rc * FD + k0);
        const float4 f0 = zp[0];
        const float4 f1 = zp[1];
        short8 av;
        av[0] = (short)f2bf(f0.x); av[1] = (short)f2bf(f0.y);
        av[2] = (short)f2bf(f0.z); av[3] = (short)f2bf(f0.w);
        av[4] = (short)f2bf(f1.x); av[5] = (short)f2bf(f1.y);
        av[6] = (short)f2bf(f1.z); av[7] = (short)f2bf(f1.w);

        #pragma unroll
        for (int nt = 0; nt < 8; ++nt) {
            const int row = nt * 16 + l16;
            const short8 b = *(const short8*)(
                ldsb + row * 256 + ((ks * 64 + kq * 16) ^ ((row & 7) << 4)));
            acc[nt] = __builtin_amdgcn_mfma_f32_16x16x32_bf16(av, b, acc[nt], 0, 0, 0);
        }
    }

    __syncthreads();   // all waves done reading Wt; reuse LDS for epilogue

    // fp32 repack: wave's 16x128 f32 tile in its 8 KB region (rows 512 B,
    // XOR-swizzled: dword-bank spread verified 2-way max).
    char* wb = ldsb + wave * 8192;
    #pragma unroll
    for (int nt = 0; nt < 8; ++nt) {
        const f32x4 v = acc[nt];
        #pragma unroll
        for (int rr = 0; rr < 4; ++rr) {
            const int row = kq * 4 + rr;            // 0..15
            const int cb4 = (nt * 16 + l16) * 4;    // byte col (f32)
            *(float*)(wb + row * 512 + (cb4 ^ ((row & 7) << 4))) = v[rr];
        }
    }
    __syncthreads();

    // read back coalesced: 32 lanes per row, 4 floats/lane -> rowmax -> int8
    #pragma unroll
    for (int i = 0; i < 8; ++i) {
        const int off = i * 1024 + lane * 16;   // 0..8191
        const int row = off >> 9;               // 0..15
        const int inr = off & 511;              // 16B-aligned within row
        const float4 v = *(const float4*)(wb + (row << 9) + (inr ^ ((row & 7) << 4)));
        float m = fmaxf(fmaxf(fabsf(v.x), fabsf(v.y)), fmaxf(fabsf(v.z), fabsf(v.w)));
        #pragma unroll
        for (int offm = 1; offm < 32; offm <<= 1)
            m = fmaxf(m, __shfl_xor(m, offm, 64));
        m = fmaxf(m, 1e-30f);
        const float inv = 127.0f / m;
        const long grow = rowbase + row;
        if (grow < nrows) {
            *(unsigned*)(u8 + grow * FD + (inr >> 2)) = pack4(v.x, v.y, v.z, v.w, inv);
            if ((lane & 31) == 0) uscale[grow] = m * (1.0f / 127.0f);
        }
    }
}

// ---------------------------------------------------------------------------
// Kernel 2: out[e] = su*sz*dot8(u8[src], z8[dst]) + b.
// 16 lanes/edge, 8 int8 (8 B) per lane -> half the gather bytes of bf16.
// Integer dot is exact; only the row quantization contributes error.
// ---------------------------------------------------------------------------
__global__ __launch_bounds__(256)
void edge8(const unsigned char* __restrict__ u8, const unsigned char* __restrict__ z8,
           const float* __restrict__ uscale, const float* __restrict__ zscale,
           const int* __restrict__ src, const int* __restrict__ dst,
           const float* __restrict__ bias, float* __restrict__ out, int E) {
    const int gw   = (blockIdx.x * 256 + (int)threadIdx.x) >> 6;
    const int lane = (int)threadIdx.x & 63;
    const int sub  = lane >> 4;
    const int l16  = lane & 15;
    const int e    = gw * 4 + sub;
    if (e >= E) return;
    const int s = src[e];
    const int t = dst[e];

    const uint2 xa = *(const uint2*)(u8 + (size_t)s * FD + l16 * 8);
    const uint2 ya = *(const uint2*)(z8 + (size_t)t * FD + l16 * 8);

    int sum = bdot4(xa.x, ya.x) + bdot4(xa.y, ya.y);
    #pragma unroll
    for (int off = 8; off >= 1; off >>= 1)
        sum += __shfl_xor(sum, off, 64);

    if (l16 == 0)
        out[e] = (float)sum * uscale[s] * zscale[t] + bias[0];
}

// ---------------------------------------------------------------------------
// Fallback (workspace too small): fused per-edge bilinear, fp32.
// ---------------------------------------------------------------------------
__global__ __launch_bounds__(128)
void bilinear_fused_fallback(const float* __restrict__ z, const float* __restrict__ Wg,
                             const int* __restrict__ src, const int* __restrict__ dst,
                             const float* __restrict__ bias, float* __restrict__ out,
                             int E) {
    __shared__ float Wl[FD * FD];
    __shared__ float zs[FD];
    __shared__ float red[2];
    for (int i = threadIdx.x; i < FD * FD; i += 128) Wl[i] = Wg[i];
    __syncthreads();
    const int j = (int)threadIdx.x;
    for (int e = blockIdx.x; e < E; e += gridDim.x) {
        const int s = src[e];
        const int t = dst[e];
        zs[j] = z[(size_t)s * FD + j];
        __syncthreads();
        float acc = 0.f;
        #pragma unroll 8
        for (int d = 0; d < FD; ++d) acc += zs[d] * Wl[d * FD + j];
        float p = acc * z[(size_t)t * FD + j];
        #pragma unroll
        for (int off = 32; off >= 1; off >>= 1)
            p += __shfl_xor(p, off, 64);
        if ((j & 63) == 0) red[j >> 6] = p;
        __syncthreads();
        if (j == 0) out[e] = red[0] + red[1] + bias[0];
        __syncthreads();
    }
}

extern "C" void kernel_launch(void* const* d_in, const int* in_sizes, int n_in,
                              void* d_out, int out_size, void* d_ws, size_t ws_size,
                              hipStream_t stream) {
    const float* z    = (const float*)d_in[0];
    const int*   ei   = (const int*)d_in[1];
    const float* W    = (const float*)d_in[2];
    const float* bias = (const float*)d_in[3];
    float* out = (float*)d_out;

    const int nrows = in_sizes[0] / FD;
    const int E     = in_sizes[1] / 2;
    const int* src = ei;
    const int* dst = ei + E;

    const size_t sz8 = (size_t)nrows * FD;                 // 12.8 MB int8 rows
    const size_t szs = (size_t)nrows * sizeof(float);      // 0.4 MB scales
    const size_t need = 2 * sz8 + 2 * szs + 256;

    if (ws_size >= need) {
        char* wsp = (char*)d_ws;
        unsigned char* u8  = (unsigned char*)wsp;
        unsigned char* z8  = (unsigned char*)(wsp + sz8);
        float* uscale = (float*)(wsp + 2 * sz8);
        float* zscale = (float*)(wsp + 2 * sz8 + szs);
        unsigned short* Wt = (unsigned short*)d_out;   // 32 KB staging; edge8
                                                       // overwrites all of d_out

        wt_kernel<<<8, 256, 0, stream>>>(W, Wt);
        zquant<<<(nrows + 7) / 8, 256, 0, stream>>>(z, z8, zscale, nrows);
        const int nb1 = (nrows + 63) / 64;
        u_mfma4<<<nb1, 256, 0, stream>>>(z, Wt, u8, uscale, nrows);
        const int nb2 = (E + 15) / 16;
        edge8<<<nb2, 256, 0, stream>>>(u8, z8, uscale, zscale, src, dst, bias, out, E);
    } else {
        bilinear_fused_fallback<<<2048, 128, 0, stream>>>(z, W, src, dst, bias, out, E);
    }
}

// Round 10
// 55.788 us; speedup vs baseline: 1.3576x; 1.3576x over previous
//
#include <hip/hip_runtime.h>

#define FD 128  // feature dim

typedef __attribute__((ext_vector_type(8))) short short8;   // 8 bf16
typedef __attribute__((ext_vector_type(4))) float f32x4;    // MFMA acc

__device__ __forceinline__ unsigned short f2bf(float f) {
    unsigned u = __float_as_uint(f);
    u += 0x7fff + ((u >> 16) & 1);   // round-to-nearest-even
    return (unsigned short)(u >> 16);
}
__device__ __forceinline__ float bf2f(unsigned short h) {
    return __uint_as_float(((unsigned)h) << 16);
}
// exact signed-int8 dot of 4 packed bytes
__device__ __forceinline__ int bdot4(unsigned x, unsigned y, int acc) {
#if __has_builtin(__builtin_amdgcn_sdot4)
    return __builtin_amdgcn_sdot4(x, y, acc, false);
#else
    acc += (((int)(x << 24)) >> 24) * (((int)(y << 24)) >> 24);
    acc += (((int)(x << 16)) >> 24) * (((int)(y << 16)) >> 24);
    acc += (((int)(x <<  8)) >> 24) * (((int)(y <<  8)) >> 24);
    acc += (((int)x) >> 24)         * (((int)y) >> 24);
    return acc;
#endif
}
__device__ __forceinline__ unsigned pack4f(float a, float b, float c, float d, float inv) {
    const int q0 = (int)rintf(a * inv), q1 = (int)rintf(b * inv);
    const int q2 = (int)rintf(c * inv), q3 = (int)rintf(d * inv);
    return (unsigned)(q0 & 255) | ((unsigned)(q1 & 255) << 8) |
           ((unsigned)(q2 & 255) << 16) | ((unsigned)(q3 & 255) << 24);
}

// ---------------------------------------------------------------------------
// Kernel 0: Wt[n][k] = bf16(W[k][n])  (128x128), short8 outputs.
// ---------------------------------------------------------------------------
__global__ void wt_kernel(const float* __restrict__ W, unsigned short* __restrict__ Wt) {
    const int tid = blockIdx.x * 256 + (int)threadIdx.x;   // 0..2047
    const int n  = tid & 127;
    const int k0 = (tid >> 7) * 8;
    short8 w;
    #pragma unroll
    for (int j = 0; j < 8; ++j) w[j] = (short)f2bf(W[(k0 + j) * FD + n]);
    *(short8*)(Wt + (size_t)n * FD + k0) = w;
}

// ---------------------------------------------------------------------------
// Kernel 1 (v5): fused u8 = int8rowquant(z @ W) AND z8 = int8rowquant(z).
// Single pass over z (51 MB). Lane k-mapping is CONTIGUOUS per lane
// (k0 = kq*32 + ks*8) so each lane owns 32 consecutive columns of its row:
// rowmax needs 2 shuffles, and z8 stores are two coalesced 16-B dwordx4.
// MFMA k-slot consistency: A lane kq slot j holds k = kq*32+ks*8+j; B is
// read from LDS at byte (kq*64 + ks*16) ^ swz so B holds the same k. The
// 4 MFMA calls partition k=0..127 (order irrelevant to the sum).
// u8 epilogue: fp32 repack through LDS -> rowmax -> int8 (as v4, verified).
// ---------------------------------------------------------------------------
__global__ __launch_bounds__(256)
void u_mfma5(const float* __restrict__ z, const unsigned short* __restrict__ Wt,
             unsigned char* __restrict__ u8, float* __restrict__ uscale,
             unsigned char* __restrict__ z8, float* __restrict__ zscale,
             int nrows) {
    __shared__ unsigned short Wl[FD * FD];  // 32 KB
    char* ldsb = (char*)Wl;
    const int tid  = (int)threadIdx.x;
    const int lane = tid & 63;
    const int wave = tid >> 6;
    const int l16  = lane & 15;
    const int kq   = lane >> 4;

    // stage Wt -> LDS, swizzled: byte = n*256 + (o ^ ((n&7)<<4))
    #pragma unroll
    for (int i = 0; i < 8; ++i) {
        const int c = i * 256 + tid;
        const int n = c >> 4;
        const int o = (c & 15) * 16;
        short8 v = *(const short8*)(Wt + (size_t)n * FD + (c & 15) * 8);
        *(short8*)(ldsb + n * 256 + (o ^ ((n & 7) << 4))) = v;
    }
    __syncthreads();

    const long rowbase = (long)blockIdx.x * 64 + wave * 16;
    const long r  = rowbase + l16;
    const long rc = (r < nrows) ? r : (long)(nrows - 1);
    const bool rok = (r < nrows);

    f32x4 acc[8];
    #pragma unroll
    for (int nt = 0; nt < 8; ++nt)
        acc[nt] = (f32x4){0.f, 0.f, 0.f, 0.f};

    short8 avk[4];           // retained bf16 A-fragments (lane's 32 columns)
    float zmax = 1e-30f;     // abs-max of the SAME bf16 values we quantize

    #pragma unroll
    for (int ks = 0; ks < 4; ++ks) {
        const int k0 = kq * 32 + ks * 8;   // contiguous per-lane slice
        const float4* zp = (const float4*)(z + rc * FD + k0);
        const float4 f0 = zp[0];
        const float4 f1 = zp[1];
        short8 av;
        av[0] = (short)f2bf(f0.x); av[1] = (short)f2bf(f0.y);
        av[2] = (short)f2bf(f0.z); av[3] = (short)f2bf(f0.w);
        av[4] = (short)f2bf(f1.x); av[5] = (short)f2bf(f1.y);
        av[6] = (short)f2bf(f1.z); av[7] = (short)f2bf(f1.w);
        avk[ks] = av;
        #pragma unroll
        for (int j = 0; j < 8; ++j)
            zmax = fmaxf(zmax, fabsf(bf2f((unsigned short)av[j])));

        #pragma unroll
        for (int nt = 0; nt < 8; ++nt) {
            const int row = nt * 16 + l16;
            const short8 b = *(const short8*)(
                ldsb + row * 256 + ((kq * 64 + ks * 16) ^ ((row & 7) << 4)));
            acc[nt] = __builtin_amdgcn_mfma_f32_16x16x32_bf16(av, b, acc[nt], 0, 0, 0);
        }
    }

    // z row-max across the 4 kq lanes of this row, then pack + store z8
    zmax = fmaxf(zmax, __shfl_xor(zmax, 16, 64));
    zmax = fmaxf(zmax, __shfl_xor(zmax, 32, 64));
    {
        const float inv = 127.0f / zmax;
        uint4 p0, p1;
        p0.x = pack4f(bf2f((unsigned short)avk[0][0]), bf2f((unsigned short)avk[0][1]),
                      bf2f((unsigned short)avk[0][2]), bf2f((unsigned short)avk[0][3]), inv);
        p0.y = pack4f(bf2f((unsigned short)avk[0][4]), bf2f((unsigned short)avk[0][5]),
                      bf2f((unsigned short)avk[0][6]), bf2f((unsigned short)avk[0][7]), inv);
        p0.z = pack4f(bf2f((unsigned short)avk[1][0]), bf2f((unsigned short)avk[1][1]),
                      bf2f((unsigned short)avk[1][2]), bf2f((unsigned short)avk[1][3]), inv);
        p0.w = pack4f(bf2f((unsigned short)avk[1][4]), bf2f((unsigned short)avk[1][5]),
                      bf2f((unsigned short)avk[1][6]), bf2f((unsigned short)avk[1][7]), inv);
        p1.x = pack4f(bf2f((unsigned short)avk[2][0]), bf2f((unsigned short)avk[2][1]),
                      bf2f((unsigned short)avk[2][2]), bf2f((unsigned short)avk[2][3]), inv);
        p1.y = pack4f(bf2f((unsigned short)avk[2][4]), bf2f((unsigned short)avk[2][5]),
                      bf2f((unsigned short)avk[2][6]), bf2f((unsigned short)avk[2][7]), inv);
        p1.z = pack4f(bf2f((unsigned short)avk[3][0]), bf2f((unsigned short)avk[3][1]),
                      bf2f((unsigned short)avk[3][2]), bf2f((unsigned short)avk[3][3]), inv);
        p1.w = pack4f(bf2f((unsigned short)avk[3][4]), bf2f((unsigned short)avk[3][5]),
                      bf2f((unsigned short)avk[3][6]), bf2f((unsigned short)avk[3][7]), inv);
        if (rok) {
            *(uint4*)(z8 + r * FD + kq * 32)      = p0;
            *(uint4*)(z8 + r * FD + kq * 32 + 16) = p1;
            if (kq == 0) zscale[r] = zmax * (1.0f / 127.0f);
        }
    }

    __syncthreads();   // all waves done reading Wt; reuse LDS for epilogue

    // fp32 repack: wave's 16x128 f32 tile in its 8 KB region (verified v4)
    char* wb = ldsb + wave * 8192;
    #pragma unroll
    for (int nt = 0; nt < 8; ++nt) {
        const f32x4 v = acc[nt];
        #pragma unroll
        for (int rr = 0; rr < 4; ++rr) {
            const int row = kq * 4 + rr;            // 0..15
            const int cb4 = (nt * 16 + l16) * 4;    // byte col (f32)
            *(float*)(wb + row * 512 + (cb4 ^ ((row & 7) << 4))) = v[rr];
        }
    }
    __syncthreads();

    #pragma unroll
    for (int i = 0; i < 8; ++i) {
        const int off = i * 1024 + lane * 16;   // 0..8191
        const int row = off >> 9;               // 0..15
        const int inr = off & 511;
        const float4 v = *(const float4*)(wb + (row << 9) + (inr ^ ((row & 7) << 4)));
        float m = fmaxf(fmaxf(fabsf(v.x), fabsf(v.y)), fmaxf(fabsf(v.z), fabsf(v.w)));
        #pragma unroll
        for (int offm = 1; offm < 32; offm <<= 1)
            m = fmaxf(m, __shfl_xor(m, offm, 64));
        m = fmaxf(m, 1e-30f);
        const float inv = 127.0f / m;
        const long grow = rowbase + row;
        if (grow < nrows) {
            *(unsigned*)(u8 + grow * FD + (inr >> 2)) = pack4f(v.x, v.y, v.z, v.w, inv);
            if ((lane & 31) == 0) uscale[grow] = m * (1.0f / 127.0f);
        }
    }
}

// ---------------------------------------------------------------------------
// Kernel 2 (pipelined): out[e] = su*sz*dot8(u8[src], z8[dst]) + b.
// 8 lanes/edge, 16 B/lane (one dwordx4 per row-slice); 8 edges/wave;
// grid-stride with a 2-deep software pipeline: chunk i+1's index, row and
// scale loads are issued BEFORE chunk i's compute, breaking the serial
// idx->gather->scale latency chain that bounded rounds 2-9 (~3500 cy/wave).
// ---------------------------------------------------------------------------
__global__ __launch_bounds__(256)
void edge8p(const unsigned char* __restrict__ u8, const unsigned char* __restrict__ z8,
            const float* __restrict__ uscale, const float* __restrict__ zscale,
            const int* __restrict__ src, const int* __restrict__ dst,
            const float* __restrict__ bias, float* __restrict__ out, int E) {
    const int tid  = (int)threadIdx.x;
    const int lane = tid & 63;
    const int sub  = lane >> 3;    // edge slot within wave (0..7)
    const int l8   = lane & 7;     // 16-B slice within the 128-B row
    const long wv  = (long)blockIdx.x * 4 + (tid >> 6);
    const long stride = (long)gridDim.x * 4 * 8;
    const float bv = bias[0];

    long e = wv * 8 + sub;
    long ec = (e < E) ? e : (long)(E - 1);
    int s = src[ec], t = dst[ec];
    uint4 xu = *((const uint4*)(u8 + (size_t)s * FD) + l8);
    uint4 xz = *((const uint4*)(z8 + (size_t)t * FD) + l8);
    float su = uscale[s], sz = zscale[t];

    while (e < E) {
        const long en  = e + stride;
        const long enc = (en < E) ? en : (long)(E - 1);
        // issue next chunk's loads (clamped; redundant at tail, harmless)
        const int s2 = src[enc], t2 = dst[enc];
        const uint4 xu2 = *((const uint4*)(u8 + (size_t)s2 * FD) + l8);
        const uint4 xz2 = *((const uint4*)(z8 + (size_t)t2 * FD) + l8);
        const float su2 = uscale[s2], sz2 = zscale[t2];

        // compute current chunk
        int sum = 0;
        sum = bdot4(xu.x, xz.x, sum);
        sum = bdot4(xu.y, xz.y, sum);
        sum = bdot4(xu.z, xz.z, sum);
        sum = bdot4(xu.w, xz.w, sum);
        sum += __shfl_xor(sum, 4, 64);
        sum += __shfl_xor(sum, 2, 64);
        sum += __shfl_xor(sum, 1, 64);
        if (l8 == 0) out[e] = (float)sum * su * sz + bv;

        // rotate
        e = en; s = s2; t = t2; xu = xu2; xz = xz2; su = su2; sz = sz2;
    }
}

// ---------------------------------------------------------------------------
// Fallback (workspace too small): fused per-edge bilinear, fp32.
// ---------------------------------------------------------------------------
__global__ __launch_bounds__(128)
void bilinear_fused_fallback(const float* __restrict__ z, const float* __restrict__ Wg,
                             const int* __restrict__ src, const int* __restrict__ dst,
                             const float* __restrict__ bias, float* __restrict__ out,
                             int E) {
    __shared__ float Wl[FD * FD];
    __shared__ float zs[FD];
    __shared__ float red[2];
    for (int i = threadIdx.x; i < FD * FD; i += 128) Wl[i] = Wg[i];
    __syncthreads();
    const int j = (int)threadIdx.x;
    for (int e = blockIdx.x; e < E; e += gridDim.x) {
        const int s = src[e];
        const int t = dst[e];
        zs[j] = z[(size_t)s * FD + j];
        __syncthreads();
        float acc = 0.f;
        #pragma unroll 8
        for (int d = 0; d < FD; ++d) acc += zs[d] * Wl[d * FD + j];
        float p = acc * z[(size_t)t * FD + j];
        #pragma unroll
        for (int off = 32; off >= 1; off >>= 1)
            p += __shfl_xor(p, off, 64);
        if ((j & 63) == 0) red[j >> 6] = p;
        __syncthreads();
        if (j == 0) out[e] = red[0] + red[1] + bias[0];
        __syncthreads();
    }
}

extern "C" void kernel_launch(void* const* d_in, const int* in_sizes, int n_in,
                              void* d_out, int out_size, void* d_ws, size_t ws_size,
                              hipStream_t stream) {
    const float* z    = (const float*)d_in[0];
    const int*   ei   = (const int*)d_in[1];
    const float* W    = (const float*)d_in[2];
    const float* bias = (const float*)d_in[3];
    float* out = (float*)d_out;

    const int nrows = in_sizes[0] / FD;
    const int E     = in_sizes[1] / 2;
    const int* src = ei;
    const int* dst = ei + E;

    const size_t sz8 = (size_t)nrows * FD;                 // 12.8 MB int8 rows
    const size_t szs = (size_t)nrows * sizeof(float);      // 0.4 MB scales
    const size_t need = 2 * sz8 + 2 * szs + 256;

    if (ws_size >= need) {
        char* wsp = (char*)d_ws;
        unsigned char* u8  = (unsigned char*)wsp;
        unsigned char* z8  = (unsigned char*)(wsp + sz8);
        float* uscale = (float*)(wsp + 2 * sz8);
        float* zscale = (float*)(wsp + 2 * sz8 + szs);
        unsigned short* Wt = (unsigned short*)d_out;   // 32 KB staging; edge8p
                                                       // overwrites all of d_out

        wt_kernel<<<8, 256, 0, stream>>>(W, Wt);
        const int nb1 = (nrows + 63) / 64;
        u_mfma5<<<nb1, 256, 0, stream>>>(z, Wt, u8, uscale, z8, zscale, nrows);
        edge8p<<<2048, 256, 0, stream>>>(u8, z8, uscale, zscale, src, dst, bias, out, E);
    } else {
        bilinear_fused_fallback<<<2048, 128, 0, stream>>>(z, W, src, dst, bias, out, E);
    }
}